// Round 11
// baseline (382.635 us; speedup 1.0000x reference)
//
#include <hip/hip_runtime.h>
#include <math.h>

// DTW 2048x2048 -- R11 = R10 byte-identical + CALIBRATION PROBE.
// 128 independent junk v_fmac_f32 per iteration (8 asm blocks x 16,
// round-robin over 4 dests -> issue-limited, not latency-limited),
// placed AFTER this iteration's DS issues and BEFORE their consumers.
// Readout (pre-committed):
//   issue-bound @1.2GHz eff clock -> ~+115us (≈380us)
//   issue-bound @2.4GHz          -> ~+57us  (≈320us)
//   stall-bound (slack at waits) -> ~unchanged (≈265us)
// This pins the regime for all subsequent optimization rounds.

#define MM 2048
#define NN 2048
#define BR 8
#define BC 8
#define NT 256
#define NB (MM / BR)                 // 256 row-blocks
#define KK 8                         // barrier period (iterations)
#define DELTA (KK + 65)              // 73: skew between adjacent waves
#define MAXSKEW (63 + 3 * DELTA)     // 282
#define NITER (NB + MAXSKEW)         // 538
#define NSP ((NITER + KK - 1) / KK)  // 68 superphases
#define RING (2 * KK)                // 16 mailbox slots per boundary
#define INFV 1e30f

__device__ __forceinline__ float wave_shr1(float x) {
    int xi = __float_as_int(x);
    int r  = __builtin_amdgcn_update_dpp(xi, xi, 0x138 /*WAVE_SHR1*/, 0xF, 0xF, false);
    return __int_as_float(r);
}

__launch_bounds__(NT, 1)
__global__ void dtw_kernel(const float* __restrict__ src,
                           const float* __restrict__ tgt,
                           float* __restrict__ out)
{
    __shared__ float  s_srcT[BR * NB];    // transposed: [r][bi]
    __shared__ float4 mbox[4][RING][2];   // row w written by wave w; read row (w+3)&3
    __shared__ float4 dump[64];           // throwaway writes, lanes != 63

    const int tid  = threadIdx.x;
    const int wv   = tid >> 6;
    const int ln   = tid & 63;
    const int skew = ln + wv * DELTA;
    const int mbthr = (wv == 0) ? 0x7fffffff : 0;
    const bool lz  = (ln == 0);
    const bool lw  = (ln == 63);

    for (int i = tid; i < MM; i += NT)
        s_srcT[(i & 7) * NB + (i >> 3)] = src[i];

    const float* tgp = tgt + tid * BC;
    float tg0 = tgp[0], tg1 = tgp[1], tg2 = tgp[2], tg3 = tgp[3],
          tg4 = tgp[4], tg5 = tgp[5], tg6 = tgp[6], tg7 = tgp[7];

    float cur0 = INFV, cur1 = INFV, cur2 = INFV, cur3 = INFV,
          cur4 = INFV, cur5 = INFV, cur6 = INFV, cur7 = INFV;

    float corner = (tid == 0) ? 0.0f : INFV;

    float rcp0 = INFV, rcp1 = INFV, rcp2 = INFV, rcp3 = INFV,
          rcp4 = INFV, rcp5 = INFV, rcp6 = INFV, rcp7 = INFV;

    float sh0 = INFV, sh1 = INFV, sh2 = INFV, sh3 = INFV,
          sh4 = INFV, sh5 = INFV, sh6 = INFV, sh7 = INFV;

    float mbA0 = INFV, mbA1 = INFV, mbA2 = INFV, mbA3 = INFV,
          mbA4 = INFV, mbA5 = INFV, mbA6 = INFV, mbA7 = INFV;
    float mbB0 = INFV, mbB1 = INFV, mbB2 = INFV, mbB3 = INFV,
          mbB4 = INFV, mbB5 = INFV, mbB6 = INFV, mbB7 = INFV;

    float psA0, psA1, psA2, psA3, psA4, psA5, psA6, psA7;
    float psB0, psB1, psB2, psB3, psB4, psB5, psB6, psB7;

    float res = 0.0f;

    // junk probe registers (opaque to the optimizer via asm "+v")
    float j0 = tg0, j1 = tg1, j2 = tg2, j3 = tg3;
    float jx = tg4, jy = tg5;

    float4* const mwrow = &mbox[wv][0][0];
    const float4* const mrrow = &mbox[(wv + 3) & 3][0][0];
    float4* const dmp = &dump[ln];

    __syncthreads();

    {
        int b0 = 0 - skew; if (b0 < 0) b0 = 0;
        int b1 = 1 - skew; if (b1 < 0) b1 = 0;
        const float* sa = s_srcT + b0;
        const float* sb = s_srcT + b1;
        psA0 = sa[0*NB]; psA1 = sa[1*NB]; psA2 = sa[2*NB]; psA3 = sa[3*NB];
        psA4 = sa[4*NB]; psA5 = sa[5*NB]; psA6 = sa[6*NB]; psA7 = sa[7*NB];
        psB0 = sb[0*NB]; psB1 = sb[1*NB]; psB2 = sb[2*NB]; psB3 = sb[3*NB];
        psB4 = sb[4*NB]; psB5 = sb[5*NB]; psB6 = sb[6*NB]; psB7 = sb[7*NB];
    }

// 16 junk v_fmac_f32, round-robin over 4 dests (dep distance 4 -> issue-bound)
#define JUNK16()                                                              \
    asm volatile(                                                             \
        "v_fmac_f32 %0, %4, %5\n\t" "v_fmac_f32 %1, %4, %5\n\t"               \
        "v_fmac_f32 %2, %4, %5\n\t" "v_fmac_f32 %3, %4, %5\n\t"               \
        "v_fmac_f32 %0, %4, %5\n\t" "v_fmac_f32 %1, %4, %5\n\t"               \
        "v_fmac_f32 %2, %4, %5\n\t" "v_fmac_f32 %3, %4, %5\n\t"               \
        "v_fmac_f32 %0, %4, %5\n\t" "v_fmac_f32 %1, %4, %5\n\t"               \
        "v_fmac_f32 %2, %4, %5\n\t" "v_fmac_f32 %3, %4, %5\n\t"               \
        "v_fmac_f32 %0, %4, %5\n\t" "v_fmac_f32 %1, %4, %5\n\t"               \
        "v_fmac_f32 %2, %4, %5\n\t" "v_fmac_f32 %3, %4, %5\n\t"               \
        : "+v"(j0), "+v"(j1), "+v"(j2), "+v"(j3) : "v"(jx), "v"(jy));

#define CEL(R, K, SV) { float up = cur##K;                                    \
                        float m  = fminf(fminf(up, l_##R), dg_##R);           \
                        float d  = (SV) - tg##K;                              \
                        float v  = fmaf(d, d, m);                             \
                        dg_##R = up; cur##K = v; l_##R = v; }

#define ITER(N_, P0,P1,P2,P3,P4,P5,P6,P7, MB0,MB1,MB2,MB3,MB4,MB5,MB6,MB7)            \
    {                                                                                 \
        const int n_ = (N_);                                                          \
        const int bi_ = n_ - skew;                                                    \
        const bool gm_ = (bi_ < mbthr);                                               \
        float t0 = gm_ ? INFV : MB0, t1 = gm_ ? INFV : MB1;                           \
        float t2 = gm_ ? INFV : MB2, t3 = gm_ ? INFV : MB3;                           \
        float t4 = gm_ ? INFV : MB4, t5 = gm_ ? INFV : MB5;                           \
        float t6 = gm_ ? INFV : MB6, t7 = gm_ ? INFV : MB7;                           \
        float lc0 = lz ? t0 : sh0, lc1 = lz ? t1 : sh1;                               \
        float lc2 = lz ? t2 : sh2, lc3 = lz ? t3 : sh3;                               \
        float lc4 = lz ? t4 : sh4, lc5 = lz ? t5 : sh5;                               \
        float lc6 = lz ? t6 : sh6, lc7 = lz ? t7 : sh7;                               \
        float l_0 = lc0, l_1 = lc1, l_2 = lc2, l_3 = lc3;                             \
        float l_4 = lc4, l_5 = lc5, l_6 = lc6, l_7 = lc7;                             \
        float dg_0 = corner, dg_1 = lc0, dg_2 = lc1, dg_3 = lc2;                      \
        float dg_4 = lc3, dg_5 = lc4, dg_6 = lc5, dg_7 = lc6;                         \
        CEL(0,0,P0)                                                                   \
        CEL(0,1,P0) CEL(1,0,P1)                                                       \
        CEL(0,2,P0) CEL(1,1,P1) CEL(2,0,P2)                                           \
        CEL(0,3,P0) CEL(1,2,P1) CEL(2,1,P2) CEL(3,0,P3)                               \
        CEL(0,4,P0) CEL(1,3,P1) CEL(2,2,P2) CEL(3,1,P3) CEL(4,0,P4)                   \
        CEL(0,5,P0) CEL(1,4,P1) CEL(2,3,P2) CEL(3,2,P3) CEL(4,1,P4) CEL(5,0,P5)       \
        CEL(0,6,P0) CEL(1,5,P1) CEL(2,4,P2) CEL(3,3,P3) CEL(4,2,P4) CEL(5,1,P5)       \
            CEL(6,0,P6)                                                               \
        CEL(0,7,P0) CEL(1,6,P1) CEL(2,5,P2) CEL(3,4,P3) CEL(4,3,P4) CEL(5,2,P5)       \
            CEL(6,1,P6) CEL(7,0,P7)                                                   \
        CEL(1,7,P1) CEL(2,6,P2) CEL(3,5,P3) CEL(4,4,P4) CEL(5,3,P5) CEL(6,2,P6)       \
            CEL(7,1,P7)                                                               \
        CEL(2,7,P2) CEL(3,6,P3) CEL(4,5,P4) CEL(5,4,P5) CEL(6,3,P6) CEL(7,2,P7)       \
        CEL(3,7,P3) CEL(4,6,P4) CEL(5,5,P5) CEL(6,4,P6) CEL(7,3,P7)                   \
        CEL(4,7,P4) CEL(5,6,P5) CEL(6,5,P6) CEL(7,4,P7)                               \
        CEL(5,7,P5) CEL(6,6,P6) CEL(7,5,P7)                                           \
        CEL(6,7,P6) CEL(7,6,P7)                                                       \
        CEL(7,7,P7)                                                                   \
        corner = lc7;                                                                 \
        rcp0 = l_0; rcp1 = l_1; rcp2 = l_2; rcp3 = l_3;                               \
        rcp4 = l_4; rcp5 = l_5; rcp6 = l_6; rcp7 = l_7;                               \
        res = (bi_ == NB - 1) ? rcp7 : res;                                           \
        {   /* unconditional mailbox write: lane63 -> real slot, others -> dump */    \
            float4* wr = lw ? (mwrow + ((n_ & (RING - 1)) << 1)) : dmp;               \
            wr[0] = make_float4(rcp0, rcp1, rcp2, rcp3);                              \
            wr[1] = make_float4(rcp4, rcp5, rcp6, rcp7);                              \
        }                                                                             \
        {   /* src prefetch for iteration n_+2 */                                     \
            int bin_ = n_ + 2 - skew;                                                 \
            bin_ = (bin_ < 0) ? 0 : bin_;                                             \
            bin_ = (bin_ > NB - 1) ? NB - 1 : bin_;                                   \
            const float* sp_ = s_srcT + bin_;                                         \
            P0 = sp_[0*NB]; P1 = sp_[1*NB]; P2 = sp_[2*NB]; P3 = sp_[3*NB];           \
            P4 = sp_[4*NB]; P5 = sp_[5*NB]; P6 = sp_[6*NB]; P7 = sp_[7*NB];           \
        }                                                                             \
        sh0 = wave_shr1(rcp0); sh1 = wave_shr1(rcp1);                                 \
        sh2 = wave_shr1(rcp2); sh3 = wave_shr1(rcp3);                                 \
        sh4 = wave_shr1(rcp4); sh5 = wave_shr1(rcp5);                                 \
        sh6 = wave_shr1(rcp6); sh7 = wave_shr1(rcp7);                                 \
        {   /* unconditional mailbox read: value for iteration n_+2 */                \
            const int sl_ = (n_ + RING - KK) & (RING - 1);                            \
            float4 m0_ = mrrow[(sl_ << 1) + 0];                                       \
            float4 m1_ = mrrow[(sl_ << 1) + 1];                                       \
            MB0 = m0_.x; MB1 = m0_.y; MB2 = m0_.z; MB3 = m0_.w;                       \
            MB4 = m1_.x; MB5 = m1_.y; MB6 = m1_.z; MB7 = m1_.w;                       \
        }                                                                             \
        /* calibration junk: 128 issue-bound VALU, placed after this iter's DS   */   \
        /* issues and before their consumers (eats waitcnt slack if any exists)  */   \
        JUNK16() JUNK16() JUNK16() JUNK16()                                           \
        JUNK16() JUNK16() JUNK16() JUNK16()                                           \
    }

    for (int sp = 0; sp < NSP; ++sp) {
        const int n0 = sp * KK;
        #pragma unroll 1
        for (int it = 0; it < KK; it += 2) {
            ITER(n0 + it,     psA0,psA1,psA2,psA3,psA4,psA5,psA6,psA7,
                              mbA0,mbA1,mbA2,mbA3,mbA4,mbA5,mbA6,mbA7)
            ITER(n0 + it + 1, psB0,psB1,psB2,psB3,psB4,psB5,psB6,psB7,
                              mbB0,mbB1,mbB2,mbB3,mbB4,mbB5,mbB6,mbB7)
        }
        __syncthreads();
    }
#undef ITER
#undef CEL
#undef JUNK16

    // keep junk regs alive (prevent DCE of the probe)
    asm volatile("" :: "v"(j0), "v"(j1), "v"(j2), "v"(j3));

    // tid 255 (wv=3,ln=63): block NB-1 computed at n = 255 + 282 = 537
    if (tid == NT - 1) out[0] = sqrtf(res);
}

extern "C" void kernel_launch(void* const* d_in, const int* in_sizes, int n_in,
                              void* d_out, int out_size, void* d_ws, size_t ws_size,
                              hipStream_t stream)
{
    (void)in_sizes; (void)n_in; (void)out_size; (void)d_ws; (void)ws_size;
    const float* source = (const float*)d_in[0];
    const float* target = (const float*)d_in[1];
    float* out = (float*)d_out;
    dtw_kernel<<<1, NT, 0, stream>>>(source, target, out);
}